// Round 16
// baseline (213.957 us; speedup 1.0000x reference)
//
#include <hip/hip_runtime.h>

typedef float        fx4 __attribute__((ext_vector_type(4)));
typedef float        fx2 __attribute__((ext_vector_type(2)));
typedef unsigned int ux4 __attribute__((ext_vector_type(4)));
typedef short        bf8 __attribute__((ext_vector_type(8)));

#define DEVI static __device__ __forceinline__

DEVI unsigned f2bf1(float f) {
  union { float f; unsigned u; } v; v.f = f;
  return (v.u + 0x7FFFu + ((v.u >> 16) & 1u)) >> 16;
}
DEVI float bf2f(unsigned h) {
  union { unsigned u; float f; } v; v.u = h << 16; return v.f;
}
DEVI unsigned cvtpk(float lo, float hi) {
  unsigned r;
  asm("v_cvt_pk_bf16_f32 %0, %1, %2" : "=v"(r) : "v"(lo), "v"(hi));
  return r;
}
DEVI void unp8(ux4 u, float* o) {
  o[0] = bf2f(u[0] & 0xffffu); o[1] = bf2f(u[0] >> 16);
  o[2] = bf2f(u[1] & 0xffffu); o[3] = bf2f(u[1] >> 16);
  o[4] = bf2f(u[2] & 0xffffu); o[5] = bf2f(u[2] >> 16);
  o[6] = bf2f(u[3] & 0xffffu); o[7] = bf2f(u[3] >> 16);
}
DEVI void gload16(const void* g, void* l) {
  __builtin_amdgcn_global_load_lds(
      (const __attribute__((address_space(1))) unsigned*)(uintptr_t)(g),
      (__attribute__((address_space(3))) unsigned*)(unsigned)(uintptr_t)(l),
      16, 0, 0);
}
// DPP butterfly add helpers (VALU pipe, no LDS)
#define DPP_ADD(v, ctrl)                                                      \
  do {                                                                        \
    union { float f; int i; } _s, _d;                                         \
    _s.f = (v);                                                               \
    _d.i = __builtin_amdgcn_update_dpp(0, _s.i, (ctrl), 0xf, 0xf, false);     \
    (v) += _d.f;                                                              \
  } while (0)
DEVI float dpp_sum16(float v) {
  DPP_ADD(v, 0xB1);   // quad_perm [1,0,3,2]
  DPP_ADD(v, 0x4E);   // quad_perm [2,3,0,1]
  DPP_ADD(v, 0x124);  // row_ror:4
  DPP_ADD(v, 0x128);  // row_ror:8
  return v;
}
DEVI float sum8(float v) {  // sum over 8-lane groups
  DPP_ADD(v, 0xB1);
  DPP_ADD(v, 0x4E);
  v += __shfl_xor(v, 4);
  return v;
}

// CPB table: f(u,v) over [-1.6,1.6]^2, 256x256. |u| <= 1.422; bilinear err ~1e-4 << 0.099.
#define TABLO (-1.6f)
#define TABD  (3.2f / 255.f)
#define TABDI (255.f / 3.2f)

// ---------------- fused prologue: weight convert + Wqd + transpose + CPB table
//  blocks [0,6048): f32->bf16 pair convert (W1,W2,W3,W4,Wout)
//  blocks [6048,6336): Wqd block-diagonal build
//  blocks [6336,7200): x transpose NCHW->NPC bf16
//  blocks [7200,7456): CPB table (256x256)
__global__ __launch_bounds__(256) void k_prep(const float* __restrict__ W1,
                                              const float* __restrict__ W2,
                                              const float* __restrict__ W3,
                                              const float* __restrict__ W4,
                                              const float* __restrict__ Wout,
                                              const float* __restrict__ Wq,
                                              const float* __restrict__ x,
                                              const float* __restrict__ cw1,
                                              const float* __restrict__ cb1,
                                              const float* __restrict__ cw2,
                                              const float* __restrict__ cb2,
                                              const float* __restrict__ cw3,
                                              const float* __restrict__ cb3,
                                              unsigned* __restrict__ dst,
                                              unsigned* __restrict__ Wqd,
                                              unsigned short* __restrict__ xT,
                                              float* __restrict__ Tb) {
  __shared__ __align__(16) char smem[19712];
  const int blk = blockIdx.x;
  const int t = threadIdx.x;
  if (blk < 6048) {
    // ---- region A: pair convert
    const size_t p = (size_t)blk * 256 + t;
    const float* s; size_t base;
    if (p < 589824)       { s = W1;   base = 0; }
    else if (p < 737280)  { s = W2;   base = 589824; }
    else if (p < 884736)  { s = W3;   base = 737280; }
    else if (p < 1474560) { s = W4;   base = 884736; }
    else                  { s = Wout; base = 1474560; }
    const size_t lp = p - base;
    dst[p] = cvtpk(s[lp * 2], s[lp * 2 + 1]);
  } else if (blk < 6336) {
    // ---- region B: block-diagonal Wqd
    const int q = (blk - 6048) * 256 + t;  // 384 rows x 192 col-pairs
    const int o = q / 192, cp = q % 192;
    const int c0 = cp * 2, c1 = c0 + 1;
    const int g = o / 48, lr = o % 48;
    const int lo = g * 48, hi = lo + 48;
    const float f0 = (c0 >= lo && c0 < hi) ? Wq[((size_t)g * 48 + lr) * 48 + (c0 - lo)] : 0.f;
    const float f1 = (c1 >= lo && c1 < hi) ? Wq[((size_t)g * 48 + lr) * 48 + (c1 - lo)] : 0.f;
    Wqd[q] = cvtpk(f0, f1);
  } else if (blk < 7200) {
    // ---- region C: transpose + bf16 convert
    float (*tile)[65] = (float(*)[65])smem;
    const int id = blk - 6336;
    const int b = id / 216, r = id % 216;
    const int c0 = (r / 9) * 64, p0 = (r % 9) * 64;
    const int tl = t & 63, th = t >> 6;
#pragma unroll
    for (int rr = 0; rr < 16; ++rr) {
      int c = th * 16 + rr;
      tile[c][tl] = x[((size_t)b * 1536 + c0 + c) * 576 + p0 + tl];
    }
    __syncthreads();
#pragma unroll
    for (int rr = 0; rr < 16; ++rr) {
      int p = th * 16 + rr;
      xT[((size_t)b * 576 + p0 + p) * 1536 + c0 + tl] = (unsigned short)f2bf1(tile[tl][p]);
    }
  } else {
    // ---- region D: CPB table build
    unsigned short* Ws = (unsigned short*)smem;          // 18432 B
    float* Cs = (float*)(smem + 18432);                  // 288 floats
    const int wid = t >> 6, lane = t & 63;
    const int lrow = lane & 15, g16 = lane >> 4;
    // stage cw2 (f32) -> fragment-ordered bf16 LDS
    for (int q = t; q < 1152; q += 256) {
      const int s = q >> 6, l = q & 63;
      const int jt = s / 3, kk = s - jt * 3;
      const int n = jt * 16 + (l & 15);
      const int k = kk * 32 + ((l >> 4) & 3) * 8;
      const float* src = cw2 + (size_t)n * 96 + k;
#pragma unroll
      for (int e = 0; e < 8; e += 2)
        *(unsigned*)&Ws[q * 8 + e] = cvtpk(src[e], src[e + 1]);
    }
    for (int q = t; q < 288; q += 256) Cs[q] = (q < 192) ? cw1[q] : cb1[q - 192];
    float cb2v[6], cw3v[6];
#pragma unroll
    for (int jt = 0; jt < 6; ++jt) {
      cb2v[jt] = cb2[jt * 16 + lrow];
      cw3v[jt] = cw3[jt * 16 + lrow];
    }
    const float cb3v = cb3[0];
    __syncthreads();
    const int base = (blk - 7200) * 256 + wid * 64;
    float uu[4], vv[4];
#pragma unroll
    for (int mt = 0; mt < 4; ++mt) {
      const int e = base + mt * 16 + lrow;
      uu[mt] = TABLO + TABD * (float)(e >> 8);
      vv[mt] = TABLO + TABD * (float)(e & 255);
    }
    bf8 afr[4][3];
#pragma unroll
    for (int kk = 0; kk < 3; ++kk) {
      const int kb = kk * 32 + g16 * 8;
      fx4 w0 = *(const fx4*)&Cs[kb * 2];
      fx4 w1 = *(const fx4*)&Cs[kb * 2 + 4];
      fx4 w2 = *(const fx4*)&Cs[kb * 2 + 8];
      fx4 w3 = *(const fx4*)&Cs[kb * 2 + 12];
      fx4 b0 = *(const fx4*)&Cs[192 + kb];
      fx4 b1 = *(const fx4*)&Cs[192 + kb + 4];
#pragma unroll
      for (int mt = 0; mt < 4; ++mt) {
        float h[8];
        h[0] = fmaxf(fmaf(w0[0], uu[mt], fmaf(w0[1], vv[mt], b0[0])), 0.f);
        h[1] = fmaxf(fmaf(w0[2], uu[mt], fmaf(w0[3], vv[mt], b0[1])), 0.f);
        h[2] = fmaxf(fmaf(w1[0], uu[mt], fmaf(w1[1], vv[mt], b0[2])), 0.f);
        h[3] = fmaxf(fmaf(w1[2], uu[mt], fmaf(w1[3], vv[mt], b0[3])), 0.f);
        h[4] = fmaxf(fmaf(w2[0], uu[mt], fmaf(w2[1], vv[mt], b1[0])), 0.f);
        h[5] = fmaxf(fmaf(w2[2], uu[mt], fmaf(w2[3], vv[mt], b1[1])), 0.f);
        h[6] = fmaxf(fmaf(w3[0], uu[mt], fmaf(w3[1], vv[mt], b1[2])), 0.f);
        h[7] = fmaxf(fmaf(w3[2], uu[mt], fmaf(w3[3], vv[mt], b1[3])), 0.f);
        ux4 pk;
        pk[0] = cvtpk(h[0], h[1]); pk[1] = cvtpk(h[2], h[3]);
        pk[2] = cvtpk(h[4], h[5]); pk[3] = cvtpk(h[6], h[7]);
        afr[mt][kk] = *(bf8*)&pk;
      }
    }
    fx4 part[4] = {};
#pragma unroll
    for (int jt = 0; jt < 6; ++jt) {
      bf8 bf0 = *(const bf8*)&Ws[((jt * 3 + 0) * 64 + lane) * 8];
      bf8 bf1 = *(const bf8*)&Ws[((jt * 3 + 1) * 64 + lane) * 8];
      bf8 bf2 = *(const bf8*)&Ws[((jt * 3 + 2) * 64 + lane) * 8];
#pragma unroll
      for (int mt = 0; mt < 4; ++mt) {
        fx4 acc = {cb2v[jt], cb2v[jt], cb2v[jt], cb2v[jt]};
        acc = __builtin_amdgcn_mfma_f32_16x16x32_bf16(afr[mt][0], bf0, acc, 0, 0, 0);
        acc = __builtin_amdgcn_mfma_f32_16x16x32_bf16(afr[mt][1], bf1, acc, 0, 0, 0);
        acc = __builtin_amdgcn_mfma_f32_16x16x32_bf16(afr[mt][2], bf2, acc, 0, 0, 0);
#pragma unroll
        for (int r = 0; r < 4; ++r)
          part[mt][r] = fmaf(fmaxf(acc[r], 0.f), cw3v[jt], part[mt][r]);
      }
    }
#pragma unroll
    for (int mt = 0; mt < 4; ++mt) {
#pragma unroll
      for (int r = 0; r < 4; ++r) part[mt][r] = dpp_sum16(part[mt][r]);
      float pv2 = part[mt][0];
      pv2 = (lrow == 1) ? part[mt][1] : pv2;
      pv2 = (lrow == 2) ? part[mt][2] : pv2;
      pv2 = (lrow == 3) ? part[mt][3] : pv2;
      if (lrow < 4) Tb[base + mt * 16 + g16 * 4 + lrow] = pv2 + cb3v;
    }
  }
}

// ---------------- bf16 MFMA GEMM, 64 x BN tile, BK=64, 3-deep pipeline w/ counted vmcnt
// FINAL epilogue (r15): old path wrote fx4 with lane-stride 2304B (4x write amplification
// on 14MB fp32 + same on resid reads). Now: acc -> LDS [m][row] (reuse Bs), then wave-per-
// m-column coalesced 256B resid-read + relu + 256B store.
#define ROWOF(q) ((((q) >> 7) << 4) + ((q) & 15))
#define KOF(q)   (((((q) >> 6) & 1) << 5) + ((((q) >> 4) & 3) << 3))
template<int BN, bool BIASADD, bool FINAL, bool RELU>
__global__ __launch_bounds__(256, 4) void k_gemm(const unsigned short* __restrict__ A,
                                                 const unsigned short* __restrict__ Wb,
                                                 const float* __restrict__ bias,
                                                 const float* __restrict__ resid,
                                                 void* __restrict__ outp, int K, int M) {
  constexpr int BCH = BN / 32;
  constexpr int NJT = BN / 32;
  __shared__ __align__(16) unsigned short As[3][4096];
  __shared__ __align__(16) unsigned short Bs[3][BN * 64];
  const int t = threadIdx.x;
  const int bz = blockIdx.z, j0 = blockIdx.x * BN, i0 = blockIdx.y * 64;
  const int lane = t & 63, wid = t >> 6;
  const int wi = wid >> 1, wj = wid & 1;
  const int lrow = lane & 15, g4 = lane >> 4;

  const unsigned short* pa0 = A + ((size_t)(bz * 576 + i0 + ROWOF(t))) * K + KOF(t);
  const unsigned short* pa1 = A + ((size_t)(bz * 576 + i0 + ROWOF(t + 256))) * K + KOF(t + 256);
  const unsigned short* pb[BCH];
#pragma unroll
  for (int c = 0; c < BCH; ++c) {
    const int q = t + c * 256;
    pb[c] = Wb + ((size_t)(j0 + ROWOF(q))) * K + KOF(q);
  }
  auto stage = [&](int buf, int ko) {
    gload16(pa0 + ko, &As[buf][t * 8]);
    gload16(pa1 + ko, &As[buf][(t + 256) * 8]);
#pragma unroll
    for (int c = 0; c < BCH; ++c) gload16(pb[c] + ko, &Bs[buf][(t + c * 256) * 8]);
  };
  fx4 acc[2][NJT] = {};
  const int nk = K >> 6;
  stage(0, 0);
  if (nk > 1) stage(1, 64);
  int cur = 0;
  for (int ki = 0; ki < nk; ++ki) {
    if (ki + 1 < nk) {
      if constexpr (BCH == 2) asm volatile("s_waitcnt vmcnt(4)" ::: "memory");
      else                    asm volatile("s_waitcnt vmcnt(6)" ::: "memory");
    } else {
      asm volatile("s_waitcnt vmcnt(0)" ::: "memory");
    }
    __builtin_amdgcn_s_barrier();
    __builtin_amdgcn_sched_barrier(0);
    asm volatile("" ::: "memory");
    if (ki + 2 < nk) {
      int b2 = cur - 1; if (b2 < 0) b2 = 2;
      stage(b2, (ki + 2) * 64);
    }
    const unsigned short* ab = &As[cur][0];
    const unsigned short* bb = &Bs[cur][0];
#pragma unroll
    for (int kk = 0; kk < 2; ++kk) {
      bf8 a0 = *(const bf8*)(ab + (((wi * 2 + 0) * 2 + kk) * 64 + lane) * 8);
      bf8 a1 = *(const bf8*)(ab + (((wi * 2 + 1) * 2 + kk) * 64 + lane) * 8);
#pragma unroll
      for (int jt = 0; jt < NJT; ++jt) {
        bf8 b = *(const bf8*)(bb + (((wj * NJT + jt) * 2 + kk) * 64 + lane) * 8);
        acc[0][jt] = __builtin_amdgcn_mfma_f32_16x16x32_bf16(a0, b, acc[0][jt], 0, 0, 0);
        acc[1][jt] = __builtin_amdgcn_mfma_f32_16x16x32_bf16(a1, b, acc[1][jt], 0, 0, 0);
      }
    }
    cur = (cur == 2) ? 0 : cur + 1;
  }
  if (FINAL) {
    // LDS transpose -> coalesced fp32 epilogue (resid + relu)
    float* sc = (float*)&Bs[0][0];  // BN x 66 floats (<= 48KB for BN=128)
    __syncthreads();
#pragma unroll
    for (int it = 0; it < 2; ++it) {
      const int lr0 = wi * 32 + it * 16 + g4 * 4;
#pragma unroll
      for (int jt = 0; jt < NJT; ++jt) {
        fx4 v = acc[it][jt];
        const int ml = wj * (BN / 2) + jt * 16 + lrow;
#pragma unroll
        for (int r = 0; r < 4; ++r) sc[ml * 66 + lr0 + r] = v[r];
      }
    }
    __syncthreads();
#pragma unroll
    for (int mi = 0; mi < BN / 4; ++mi) {
      const int m = wid * (BN / 4) + mi;
      const float val = sc[m * 66 + lane];
      const size_t gi = ((size_t)bz * M + j0 + m) * 576 + i0 + lane;
      ((float*)outp)[gi] = fmaxf(val + resid[gi], 0.f);
    }
    return;
  }
#pragma unroll
  for (int it = 0; it < 2; ++it) {
    const int row0 = i0 + wi * 32 + it * 16 + g4 * 4;
#pragma unroll
    for (int jt = 0; jt < NJT; ++jt) {
      fx4 v = acc[it][jt];
      const int m = j0 + wj * (BN / 2) + jt * 16 + lrow;
      if (BIASADD) {
        float bv = bias[m];
        v[0] += bv; v[1] += bv; v[2] += bv; v[3] += bv;
      }
      unsigned short* o = (unsigned short*)outp;
#pragma unroll
      for (int r = 0; r < 4; ++r) {
        const float ov = RELU ? fmaxf(v[r], 0.f) : v[r];
        o[((size_t)(bz * 576) + row0 + r) * M + m] = (unsigned short)f2bf1(ov);
      }
    }
  }
}
#undef ROWOF
#undef KOF

// ---------------- fused offsets -> grid-sample -> k/v proj, lane-parallel
__global__ __launch_bounds__(256, 2) void k_sample(const unsigned short* __restrict__ qT,
                                                   const unsigned short* __restrict__ h2T,
                                                   const float* __restrict__ Wdw,
                                                   const float* __restrict__ bdw,
                                                   const float* __restrict__ Wpw,
                                                   const float* __restrict__ Wk,
                                                   const float* __restrict__ Wv,
                                                   float* __restrict__ vgrid,
                                                   float* __restrict__ kT,
                                                   float* __restrict__ vT) {
  __shared__ float vg[32];                              // 16 pos x 2
  __shared__ __align__(16) unsigned short kvls[768];    // 16 pos x 48 bf16
  const int blk = blockIdx.x;
  const int bg = blk >> 2, pg = blk & 3;
  const int b = bg >> 3, g = bg & 7;
  const int t = threadIdx.x;
  const int pl = t >> 4;        // local pos 0..15
  const int cq = t & 15;        // channel slice (3 ch)
  const int pos = pg * 16 + pl;
  const int oy = pos >> 3, ox = pos & 7;
  const int ch0 = cq * 3;
  // ---- phase A: depthwise 3x3/s3 + gelu + 1x1(2) via lane-parallel reduce
  float s0 = bdw[ch0], s1 = bdw[ch0 + 1], s2 = bdw[ch0 + 2];
#pragma unroll
  for (int ky = 0; ky < 3; ++ky) {
#pragma unroll
    for (int kx = 0; kx < 3; ++kx) {
      const unsigned short* rp =
          qT + ((size_t)b * 576 + (oy * 3 + ky) * 24 + ox * 3 + kx) * 384 + g * 48 + ch0;
      const int tap = ky * 3 + kx;
      s0 = fmaf(bf2f(rp[0]), Wdw[(ch0 + 0) * 9 + tap], s0);
      s1 = fmaf(bf2f(rp[1]), Wdw[(ch0 + 1) * 9 + tap], s1);
      s2 = fmaf(bf2f(rp[2]), Wdw[(ch0 + 2) * 9 + tap], s2);
    }
  }
  float a0 = 0.f, a1 = 0.f;
  {
    const float z0 = s0, z1 = s1, z2 = s2;
    const float g0 = 0.5f * z0 * (1.f + erff(z0 * 0.70710678118654752f));
    const float g1 = 0.5f * z1 * (1.f + erff(z1 * 0.70710678118654752f));
    const float g2 = 0.5f * z2 * (1.f + erff(z2 * 0.70710678118654752f));
    a0 = g0 * Wpw[ch0] + g1 * Wpw[ch0 + 1] + g2 * Wpw[ch0 + 2];
    a1 = g0 * Wpw[48 + ch0] + g1 * Wpw[48 + ch0 + 1] + g2 * Wpw[48 + ch0 + 2];
  }
  a0 = dpp_sum16(a0);
  a1 = dpp_sum16(a1);
  const float gx = ((float)ox + tanhf(a0) * 4.f) * (2.f / 7.f) - 1.f;
  const float gy = ((float)oy + tanhf(a1) * 4.f) * (2.f / 7.f) - 1.f;
  if (cq == 0) {
    vg[pl * 2 + 0] = gx; vg[pl * 2 + 1] = gy;
    vgrid[bg * 128 + pos * 2 + 0] = gx;
    vgrid[bg * 128 + pos * 2 + 1] = gy;
  }
  __syncthreads();
  // ---- phase B: bilinear grid sample (3 ch per thread)
  {
    const float nx = vg[pl * 2 + 0], ny = vg[pl * 2 + 1];
    const float xs = ((nx + 1.f) * 24.f - 1.f) * 0.5f;
    const float ys = ((ny + 1.f) * 24.f - 1.f) * 0.5f;
    const float x0f = floorf(xs), y0f = floorf(ys);
    const float wx = xs - x0f, wy = ys - y0f;
    const int x0 = (int)x0f, y0 = (int)y0f;
    float c0a = 0.f, c1a = 0.f, c2a = 0.f;
    const float tw[4] = {(1.f - wx) * (1.f - wy), wx * (1.f - wy), (1.f - wx) * wy, wx * wy};
    const int tx[4] = {x0, x0 + 1, x0, x0 + 1};
    const int ty[4] = {y0, y0, y0 + 1, y0 + 1};
#pragma unroll
    for (int tp = 0; tp < 4; ++tp) {
      const int ix = tx[tp], iy = ty[tp];
      const float w = tw[tp] * ((ix >= 0 && ix < 24 && iy >= 0 && iy < 24) ? 1.f : 0.f);
      const int cx = min(max(ix, 0), 23), cy = min(max(iy, 0), 23);
      const unsigned short* rp = h2T + ((size_t)b * 576 + cy * 24 + cx) * 384 + g * 48 + ch0;
      c0a = fmaf(bf2f(rp[0]), w, c0a);
      c1a = fmaf(bf2f(rp[1]), w, c1a);
      c2a = fmaf(bf2f(rp[2]), w, c2a);
    }
    kvls[pl * 48 + ch0 + 0] = (unsigned short)f2bf1(c0a);
    kvls[pl * 48 + ch0 + 1] = (unsigned short)f2bf1(c1a);
    kvls[pl * 48 + ch0 + 2] = (unsigned short)f2bf1(c2a);
  }
  __syncthreads();
  // ---- phase C: k/v grouped 1x1 from LDS; 768 outputs, 3 per thread
#pragma unroll
  for (int r = 0; r < 3; ++r) {
    const int idx = t + r * 256;
    const int j = idx / 48, o = idx % 48;
    const unsigned short* rp = &kvls[j * 48];
    const float* wkp = Wk + ((size_t)g * 48 + o) * 48;
    const float* wvp = Wv + ((size_t)g * 48 + o) * 48;
    float ak = 0.f, av = 0.f;
#pragma unroll
    for (int c8 = 0; c8 < 6; ++c8) {
      ux4 u = *(const ux4*)(rp + c8 * 8);
      float va[8]; unp8(u, va);
      fx4 wk0 = *(const fx4*)(wkp + c8 * 8); fx4 wk1 = *(const fx4*)(wkp + c8 * 8 + 4);
      fx4 wv0 = *(const fx4*)(wvp + c8 * 8); fx4 wv1 = *(const fx4*)(wvp + c8 * 8 + 4);
#pragma unroll
      for (int e = 0; e < 4; ++e) {
        ak = fmaf(va[e], wk0[e], ak); ak = fmaf(va[4 + e], wk1[e], ak);
        av = fmaf(va[e], wv0[e], av); av = fmaf(va[4 + e], wv1[e], av);
      }
    }
    kT[(size_t)bg * 3072 + (pg * 16 + j) * 48 + o] = ak;
    vT[(size_t)bg * 3072 + (pg * 16 + j) * 48 + o] = av;
  }
}

// ---------------- attention v3: 2 q-tiles/block (stage amortized), 8 lanes/query
__global__ __launch_bounds__(256) void k_attn(const unsigned short* __restrict__ qT,
                                              const float* __restrict__ kT,
                                              const float* __restrict__ vT,
                                              const float* __restrict__ vgrid,
                                              const float* __restrict__ Tb,
                                              unsigned short* __restrict__ aoT) {
  __shared__ __align__(16) float kls[3360];
  __shared__ __align__(16) float vls[3360];
  __shared__ float vgls[128];
  const int t = threadIdx.x;
  const int ic = blockIdx.x, h = blockIdx.y, b = blockIdx.z;
  const int bg = b * 8 + h;
  // stage K/V rows with swizzle: row j at j*52 + (j>>3)*4 floats
  {
    const int j = t >> 2, qt = t & 3;
    const float* sk = kT + (size_t)bg * 3072 + j * 48 + qt * 12;
    const float* sv = vT + (size_t)bg * 3072 + j * 48 + qt * 12;
    float* dk = kls + j * 52 + (j >> 3) * 4 + qt * 12;
    float* dv = vls + j * 52 + (j >> 3) * 4 + qt * 12;
#pragma unroll
    for (int e = 0; e < 3; ++e) {
      ((fx4*)dk)[e] = ((const fx4*)sk)[e];
      ((fx4*)dv)[e] = ((const fx4*)sv)[e];
    }
  }
  if (t < 128) vgls[t] = vgrid[bg * 128 + t];
  __syncthreads();
  const int kg = t & 7;
  const int rowbase = kg * 420;  // kg*8*52 + kg*4
  const float scale = 0.14433756729740643f;  // 48^-0.5
#pragma unroll 1
  for (int half = 0; half < 2; ++half) {
    const int qi = ic * 64 + half * 32 + (t >> 3);
    const unsigned short* qp = qT + ((size_t)b * 576 + qi) * 384 + h * 48;
    float s[8] = {0.f, 0.f, 0.f, 0.f, 0.f, 0.f, 0.f, 0.f};
#pragma unroll
    for (int c8 = 0; c8 < 6; ++c8) {
      ux4 u = *(const ux4*)(qp + c8 * 8);
      float qv[8]; unp8(u, qv);
#pragma unroll
      for (int it = 0; it < 8; ++it) {
        const float* kr = kls + rowbase + it * 52 + c8 * 8;
        fx4 k0 = *(const fx4*)kr, k1 = *(const fx4*)(kr + 4);
        s[it] = fmaf(qv[0], k0[0], s[it]); s[it] = fmaf(qv[1], k0[1], s[it]);
        s[it] = fmaf(qv[2], k0[2], s[it]); s[it] = fmaf(qv[3], k0[3], s[it]);
        s[it] = fmaf(qv[4], k1[0], s[it]); s[it] = fmaf(qv[5], k1[1], s[it]);
        s[it] = fmaf(qv[6], k1[2], s[it]); s[it] = fmaf(qv[7], k1[3], s[it]);
      }
    }
    const float qnx = (float)(qi % 24) * (2.f / 23.f) - 1.f;
    const float qny = (float)(qi / 24) * (2.f / 23.f) - 1.f;
#pragma unroll
    for (int it = 0; it < 8; ++it) {
      const int j = kg * 8 + it;
      const float pu = qnx - vgls[j * 2 + 0];
      const float pv = qny - vgls[j * 2 + 1];
      const float u = copysignf(__logf(1.f + fabsf(pu)), pu);
      const float v = copysignf(__logf(1.f + fabsf(pv)), pv);
      float tu = (u - TABLO) * TABDI;
      float tv = (v - TABLO) * TABDI;
      int iu = (int)floorf(tu); iu = min(max(iu, 0), 254);
      int iv = (int)floorf(tv); iv = min(max(iv, 0), 254);
      const float fu = tu - (float)iu;
      const float fv = tv - (float)iv;
      const float* r0 = Tb + iu * 256 + iv;
      const float a = r0[0], bb2 = r0[1], c = r0[256], d = r0[257];
      const float top = fmaf(fv, bb2 - a, a);
      const float bot = fmaf(fv, d - c, c);
      s[it] = fmaf(s[it], scale, fmaf(fu, bot - top, top));
    }
    float mx = s[0];
#pragma unroll
    for (int it = 1; it < 8; ++it) mx = fmaxf(mx, s[it]);
    mx = fmaxf(mx, __shfl_xor(mx, 1));
    mx = fmaxf(mx, __shfl_xor(mx, 2));
    mx = fmaxf(mx, __shfl_xor(mx, 4));
    float sum = 0.f;
#pragma unroll
    for (int it = 0; it < 8; ++it) { s[it] = __expf(s[it] - mx); sum += s[it]; }
    sum = sum8(sum);
    const float inv = 1.f / sum;
#pragma unroll
    for (int it = 0; it < 8; ++it) s[it] *= inv;
    float keep[8];
#pragma unroll
    for (int c8 = 0; c8 < 6; ++c8) {
      float a8[8] = {0.f, 0.f, 0.f, 0.f, 0.f, 0.f, 0.f, 0.f};
#pragma unroll
      for (int it = 0; it < 8; ++it) {
        const float p = s[it];
        const float* vr = vls + rowbase + it * 52 + c8 * 8;
        fx4 v0 = *(const fx4*)vr, v1 = *(const fx4*)(vr + 4);
        a8[0] = fmaf(p, v0[0], a8[0]); a8[1] = fmaf(p, v0[1], a8[1]);
        a8[2] = fmaf(p, v0[2], a8[2]); a8[3] = fmaf(p, v0[3], a8[3]);
        a8[4] = fmaf(p, v1[0], a8[4]); a8[5] = fmaf(p, v1[1], a8[5]);
        a8[6] = fmaf(p, v1[2], a8[6]); a8[7] = fmaf(p, v1[3], a8[7]);
      }
#pragma unroll
      for (int e = 0; e < 8; ++e) {
        a8[e] = sum8(a8[e]);
        keep[e] = (kg == c8) ? a8[e] : keep[e];
      }
    }
    if (kg < 6) {
      unsigned* op32 = (unsigned*)(aoT + ((size_t)b * 576 + qi) * 384 + h * 48 + kg * 8);
      op32[0] = cvtpk(keep[0], keep[1]);
      op32[1] = cvtpk(keep[2], keep[3]);
      op32[2] = cvtpk(keep[4], keep[5]);
      op32[3] = cvtpk(keep[6], keep[7]);
    }
  }
}

extern "C" void kernel_launch(void* const* d_in, const int* in_sizes, int n_in,
                              void* d_out, int out_size, void* d_ws, size_t ws_size,
                              hipStream_t stream) {
  (void)in_sizes; (void)n_in; (void)out_size; (void)ws_size;
  const float* x    = (const float*)d_in[0];
  const float* W1   = (const float*)d_in[1];
  const float* W2   = (const float*)d_in[2];
  const float* W3   = (const float*)d_in[3];
  const float* W4   = (const float*)d_in[4];
  const float* Wq   = (const float*)d_in[5];
  const float* Wk   = (const float*)d_in[6];
  const float* Wv   = (const float*)d_in[7];
  const float* Wdw  = (const float*)d_in[8];
  const float* bdw  = (const float*)d_in[9];
  const float* Wpw  = (const float*)d_in[10];
  const float* cw1  = (const float*)d_in[11];
  const float* cb1  = (const float*)d_in[12];
  const float* cw2  = (const float*)d_in[13];
  const float* cb2  = (const float*)d_in[14];
  const float* cw3  = (const float*)d_in[15];
  const float* cb3  = (const float*)d_in[16];
  const float* Wout = (const float*)d_in[17];
  const float* bout = (const float*)d_in[18];

  char* ws = (char*)d_ws;
  size_t off = 0;
  auto alloc = [&](size_t bytes) {
    void* p = ws + off;
    off += (bytes + 255) & ~(size_t)255;
    return p;
  };
  unsigned short* xT  = (unsigned short*)alloc((size_t)4 * 576 * 1536 * 2);
  unsigned short* h1T = (unsigned short*)alloc((size_t)4 * 576 * 768 * 2);
  unsigned short* h2T = (unsigned short*)alloc((size_t)4 * 576 * 384 * 2);
  unsigned short* qT  = (unsigned short*)alloc((size_t)4 * 576 * 384 * 2);
  unsigned short* aoT = (unsigned short*)alloc((size_t)4 * 576 * 384 * 2);
  unsigned short* AT  = (unsigned short*)alloc((size_t)4 * 576 * 384 * 2);
  unsigned short* h3T = (unsigned short*)alloc((size_t)4 * 576 * 768 * 2);
  float* vgrid = (float*)alloc((size_t)32 * 64 * 2 * 4);
  float* kTb  = (float*)alloc((size_t)32 * 64 * 48 * 4);
  float* vTb  = (float*)alloc((size_t)32 * 64 * 48 * 4);
  float* Tb    = (float*)alloc((size_t)256 * 256 * 4);  // CPB table
  unsigned short* Wcvt = (unsigned short*)alloc((size_t)3096576 * 2);  // bf16 weights
  unsigned short* Wqd  = (unsigned short*)alloc((size_t)384 * 384 * 2);  // block-diag q weight
  const unsigned short* W1b   = Wcvt;
  const unsigned short* W2b   = Wcvt + 1179648;
  const unsigned short* W3b   = Wcvt + 1474560;
  const unsigned short* W4b   = Wcvt + 1769472;
  const unsigned short* Woutb = Wcvt + 2949120;

  k_prep<<<7456, 256, 0, stream>>>(W1, W2, W3, W4, Wout, Wq, x,
                                   cw1, cb1, cw2, cb2, cw3, cb3,
                                   (unsigned*)Wcvt, (unsigned*)Wqd, xT, Tb);
  k_gemm<128, false, false, true><<<dim3(6, 9, 4), 256, 0, stream>>>(xT, W1b, nullptr, nullptr, h1T, 1536, 768);
  k_gemm<64, false, false, true><<<dim3(6, 9, 4), 256, 0, stream>>>(h1T, W2b, nullptr, nullptr, h2T, 768, 384);
  k_gemm<64, false, false, false><<<dim3(6, 9, 4), 256, 0, stream>>>(h2T, Wqd, nullptr, nullptr, qT, 384, 384);
  k_sample<<<128, 256, 0, stream>>>(qT, h2T, Wdw, bdw, Wpw, Wk, Wv, vgrid, kTb, vTb);
  k_attn<<<dim3(9, 8, 4), 256, 0, stream>>>(qT, kTb, vTb, vgrid, Tb, aoT);
  k_gemm<64, true, false, true><<<dim3(6, 9, 4), 256, 0, stream>>>(aoT, Woutb, bout, nullptr, AT, 384, 384);
  k_gemm<128, false, false, true><<<dim3(6, 9, 4), 256, 0, stream>>>(AT, W3b, nullptr, nullptr, h3T, 384, 768);
  k_gemm<128, false, true, true><<<dim3(12, 9, 4), 256, 0, stream>>>(h3T, W4b, nullptr, x, d_out, 768, 1536);
}

// Round 17
// 109.054 us; speedup vs baseline: 1.9619x; 1.9619x over previous
//
#include <hip/hip_runtime.h>

typedef float        fx4 __attribute__((ext_vector_type(4)));
typedef float        fx2 __attribute__((ext_vector_type(2)));
typedef unsigned int ux4 __attribute__((ext_vector_type(4)));
typedef short        bf8 __attribute__((ext_vector_type(8)));

#define DEVI static __device__ __forceinline__

DEVI unsigned f2bf1(float f) {
  union { float f; unsigned u; } v; v.f = f;
  return (v.u + 0x7FFFu + ((v.u >> 16) & 1u)) >> 16;
}
DEVI float bf2f(unsigned h) {
  union { unsigned u; float f; } v; v.u = h << 16; return v.f;
}
DEVI unsigned cvtpk(float lo, float hi) {
  unsigned r;
  asm("v_cvt_pk_bf16_f32 %0, %1, %2" : "=v"(r) : "v"(lo), "v"(hi));
  return r;
}
DEVI void unp8(ux4 u, float* o) {
  o[0] = bf2f(u[0] & 0xffffu); o[1] = bf2f(u[0] >> 16);
  o[2] = bf2f(u[1] & 0xffffu); o[3] = bf2f(u[1] >> 16);
  o[4] = bf2f(u[2] & 0xffffu); o[5] = bf2f(u[2] >> 16);
  o[6] = bf2f(u[3] & 0xffffu); o[7] = bf2f(u[3] >> 16);
}
DEVI void gload16(const void* g, void* l) {
  __builtin_amdgcn_global_load_lds(
      (const __attribute__((address_space(1))) unsigned*)(uintptr_t)(g),
      (__attribute__((address_space(3))) unsigned*)(unsigned)(uintptr_t)(l),
      16, 0, 0);
}
// DPP butterfly add helpers (VALU pipe, no LDS)
#define DPP_ADD(v, ctrl)                                                      \
  do {                                                                        \
    union { float f; int i; } _s, _d;                                         \
    _s.f = (v);                                                               \
    _d.i = __builtin_amdgcn_update_dpp(0, _s.i, (ctrl), 0xf, 0xf, false);     \
    (v) += _d.f;                                                              \
  } while (0)
DEVI float dpp_sum16(float v) {
  DPP_ADD(v, 0xB1);   // quad_perm [1,0,3,2]
  DPP_ADD(v, 0x4E);   // quad_perm [2,3,0,1]
  DPP_ADD(v, 0x124);  // row_ror:4
  DPP_ADD(v, 0x128);  // row_ror:8
  return v;
}
DEVI float sum8(float v) {  // sum over 8-lane groups
  DPP_ADD(v, 0xB1);
  DPP_ADD(v, 0x4E);
  v += __shfl_xor(v, 4);
  return v;
}

// CPB table: f(u,v) over [-1.6,1.6]^2, 256x256. |u| <= 1.422; bilinear err ~1e-4 << 0.099.
#define TABLO (-1.6f)
#define TABD  (3.2f / 255.f)
#define TABDI (255.f / 3.2f)

// ---------------- fused prologue: weight convert + Wqd + transpose + CPB table
//  blocks [0,6048): f32->bf16 pair convert (W1,W2,W3,W4,Wout)
//  blocks [6048,6336): Wqd block-diagonal build
//  blocks [6336,7200): x transpose NCHW->NPC bf16
//  blocks [7200,7456): CPB table (256x256)
__global__ __launch_bounds__(256) void k_prep(const float* __restrict__ W1,
                                              const float* __restrict__ W2,
                                              const float* __restrict__ W3,
                                              const float* __restrict__ W4,
                                              const float* __restrict__ Wout,
                                              const float* __restrict__ Wq,
                                              const float* __restrict__ x,
                                              const float* __restrict__ cw1,
                                              const float* __restrict__ cb1,
                                              const float* __restrict__ cw2,
                                              const float* __restrict__ cb2,
                                              const float* __restrict__ cw3,
                                              const float* __restrict__ cb3,
                                              unsigned* __restrict__ dst,
                                              unsigned* __restrict__ Wqd,
                                              unsigned short* __restrict__ xT,
                                              float* __restrict__ Tb) {
  __shared__ __align__(16) char smem[19712];
  const int blk = blockIdx.x;
  const int t = threadIdx.x;
  if (blk < 6048) {
    // ---- region A: pair convert
    const size_t p = (size_t)blk * 256 + t;
    const float* s; size_t base;
    if (p < 589824)       { s = W1;   base = 0; }
    else if (p < 737280)  { s = W2;   base = 589824; }
    else if (p < 884736)  { s = W3;   base = 737280; }
    else if (p < 1474560) { s = W4;   base = 884736; }
    else                  { s = Wout; base = 1474560; }
    const size_t lp = p - base;
    dst[p] = cvtpk(s[lp * 2], s[lp * 2 + 1]);
  } else if (blk < 6336) {
    // ---- region B: block-diagonal Wqd
    const int q = (blk - 6048) * 256 + t;  // 384 rows x 192 col-pairs
    const int o = q / 192, cp = q % 192;
    const int c0 = cp * 2, c1 = c0 + 1;
    const int g = o / 48, lr = o % 48;
    const int lo = g * 48, hi = lo + 48;
    const float f0 = (c0 >= lo && c0 < hi) ? Wq[((size_t)g * 48 + lr) * 48 + (c0 - lo)] : 0.f;
    const float f1 = (c1 >= lo && c1 < hi) ? Wq[((size_t)g * 48 + lr) * 48 + (c1 - lo)] : 0.f;
    Wqd[q] = cvtpk(f0, f1);
  } else if (blk < 7200) {
    // ---- region C: transpose + bf16 convert
    float (*tile)[65] = (float(*)[65])smem;
    const int id = blk - 6336;
    const int b = id / 216, r = id % 216;
    const int c0 = (r / 9) * 64, p0 = (r % 9) * 64;
    const int tl = t & 63, th = t >> 6;
#pragma unroll
    for (int rr = 0; rr < 16; ++rr) {
      int c = th * 16 + rr;
      tile[c][tl] = x[((size_t)b * 1536 + c0 + c) * 576 + p0 + tl];
    }
    __syncthreads();
#pragma unroll
    for (int rr = 0; rr < 16; ++rr) {
      int p = th * 16 + rr;
      xT[((size_t)b * 576 + p0 + p) * 1536 + c0 + tl] = (unsigned short)f2bf1(tile[tl][p]);
    }
  } else {
    // ---- region D: CPB table build
    unsigned short* Ws = (unsigned short*)smem;          // 18432 B
    float* Cs = (float*)(smem + 18432);                  // 288 floats
    const int wid = t >> 6, lane = t & 63;
    const int lrow = lane & 15, g16 = lane >> 4;
    // stage cw2 (f32) -> fragment-ordered bf16 LDS
    for (int q = t; q < 1152; q += 256) {
      const int s = q >> 6, l = q & 63;
      const int jt = s / 3, kk = s - jt * 3;
      const int n = jt * 16 + (l & 15);
      const int k = kk * 32 + ((l >> 4) & 3) * 8;
      const float* src = cw2 + (size_t)n * 96 + k;
#pragma unroll
      for (int e = 0; e < 8; e += 2)
        *(unsigned*)&Ws[q * 8 + e] = cvtpk(src[e], src[e + 1]);
    }
    for (int q = t; q < 288; q += 256) Cs[q] = (q < 192) ? cw1[q] : cb1[q - 192];
    float cb2v[6], cw3v[6];
#pragma unroll
    for (int jt = 0; jt < 6; ++jt) {
      cb2v[jt] = cb2[jt * 16 + lrow];
      cw3v[jt] = cw3[jt * 16 + lrow];
    }
    const float cb3v = cb3[0];
    __syncthreads();
    const int base = (blk - 7200) * 256 + wid * 64;
    float uu[4], vv[4];
#pragma unroll
    for (int mt = 0; mt < 4; ++mt) {
      const int e = base + mt * 16 + lrow;
      uu[mt] = TABLO + TABD * (float)(e >> 8);
      vv[mt] = TABLO + TABD * (float)(e & 255);
    }
    bf8 afr[4][3];
#pragma unroll
    for (int kk = 0; kk < 3; ++kk) {
      const int kb = kk * 32 + g16 * 8;
      fx4 w0 = *(const fx4*)&Cs[kb * 2];
      fx4 w1 = *(const fx4*)&Cs[kb * 2 + 4];
      fx4 w2 = *(const fx4*)&Cs[kb * 2 + 8];
      fx4 w3 = *(const fx4*)&Cs[kb * 2 + 12];
      fx4 b0 = *(const fx4*)&Cs[192 + kb];
      fx4 b1 = *(const fx4*)&Cs[192 + kb + 4];
#pragma unroll
      for (int mt = 0; mt < 4; ++mt) {
        float h[8];
        h[0] = fmaxf(fmaf(w0[0], uu[mt], fmaf(w0[1], vv[mt], b0[0])), 0.f);
        h[1] = fmaxf(fmaf(w0[2], uu[mt], fmaf(w0[3], vv[mt], b0[1])), 0.f);
        h[2] = fmaxf(fmaf(w1[0], uu[mt], fmaf(w1[1], vv[mt], b0[2])), 0.f);
        h[3] = fmaxf(fmaf(w1[2], uu[mt], fmaf(w1[3], vv[mt], b0[3])), 0.f);
        h[4] = fmaxf(fmaf(w2[0], uu[mt], fmaf(w2[1], vv[mt], b1[0])), 0.f);
        h[5] = fmaxf(fmaf(w2[2], uu[mt], fmaf(w2[3], vv[mt], b1[1])), 0.f);
        h[6] = fmaxf(fmaf(w3[0], uu[mt], fmaf(w3[1], vv[mt], b1[2])), 0.f);
        h[7] = fmaxf(fmaf(w3[2], uu[mt], fmaf(w3[3], vv[mt], b1[3])), 0.f);
        ux4 pk;
        pk[0] = cvtpk(h[0], h[1]); pk[1] = cvtpk(h[2], h[3]);
        pk[2] = cvtpk(h[4], h[5]); pk[3] = cvtpk(h[6], h[7]);
        afr[mt][kk] = *(bf8*)&pk;
      }
    }
    fx4 part[4] = {};
#pragma unroll
    for (int jt = 0; jt < 6; ++jt) {
      bf8 bf0 = *(const bf8*)&Ws[((jt * 3 + 0) * 64 + lane) * 8];
      bf8 bf1 = *(const bf8*)&Ws[((jt * 3 + 1) * 64 + lane) * 8];
      bf8 bf2 = *(const bf8*)&Ws[((jt * 3 + 2) * 64 + lane) * 8];
#pragma unroll
      for (int mt = 0; mt < 4; ++mt) {
        fx4 acc = {cb2v[jt], cb2v[jt], cb2v[jt], cb2v[jt]};
        acc = __builtin_amdgcn_mfma_f32_16x16x32_bf16(afr[mt][0], bf0, acc, 0, 0, 0);
        acc = __builtin_amdgcn_mfma_f32_16x16x32_bf16(afr[mt][1], bf1, acc, 0, 0, 0);
        acc = __builtin_amdgcn_mfma_f32_16x16x32_bf16(afr[mt][2], bf2, acc, 0, 0, 0);
#pragma unroll
        for (int r = 0; r < 4; ++r)
          part[mt][r] = fmaf(fmaxf(acc[r], 0.f), cw3v[jt], part[mt][r]);
      }
    }
#pragma unroll
    for (int mt = 0; mt < 4; ++mt) {
#pragma unroll
      for (int r = 0; r < 4; ++r) part[mt][r] = dpp_sum16(part[mt][r]);
      float pv2 = part[mt][0];
      pv2 = (lrow == 1) ? part[mt][1] : pv2;
      pv2 = (lrow == 2) ? part[mt][2] : pv2;
      pv2 = (lrow == 3) ? part[mt][3] : pv2;
      if (lrow < 4) Tb[base + mt * 16 + g16 * 4 + lrow] = pv2 + cb3v;
    }
  }
}

// ---------------- bf16 MFMA GEMM, 64 x BN tile, BK=64, 3-deep pipeline w/ counted vmcnt
// FINAL epilogue: acc -> LDS [m][row] (reuse Bs), then coalesced resid+relu+store.
#define ROWOF(q) ((((q) >> 7) << 4) + ((q) & 15))
#define KOF(q)   (((((q) >> 6) & 1) << 5) + ((((q) >> 4) & 3) << 3))
template<int BN, bool BIASADD, bool FINAL, bool RELU>
__global__ __launch_bounds__(256, 4) void k_gemm(const unsigned short* __restrict__ A,
                                                 const unsigned short* __restrict__ Wb,
                                                 const float* __restrict__ bias,
                                                 const float* __restrict__ resid,
                                                 void* __restrict__ outp, int K, int M) {
  constexpr int BCH = BN / 32;
  constexpr int NJT = BN / 32;
  __shared__ __align__(16) unsigned short As[3][4096];
  __shared__ __align__(16) unsigned short Bs[3][BN * 64];
  const int t = threadIdx.x;
  const int bz = blockIdx.z, j0 = blockIdx.x * BN, i0 = blockIdx.y * 64;
  const int lane = t & 63, wid = t >> 6;
  const int wi = wid >> 1, wj = wid & 1;
  const int lrow = lane & 15, g4 = lane >> 4;

  const unsigned short* pa0 = A + ((size_t)(bz * 576 + i0 + ROWOF(t))) * K + KOF(t);
  const unsigned short* pa1 = A + ((size_t)(bz * 576 + i0 + ROWOF(t + 256))) * K + KOF(t + 256);
  const unsigned short* pb[BCH];
#pragma unroll
  for (int c = 0; c < BCH; ++c) {
    const int q = t + c * 256;
    pb[c] = Wb + ((size_t)(j0 + ROWOF(q))) * K + KOF(q);
  }
  auto stage = [&](int buf, int ko) {
    gload16(pa0 + ko, &As[buf][t * 8]);
    gload16(pa1 + ko, &As[buf][(t + 256) * 8]);
#pragma unroll
    for (int c = 0; c < BCH; ++c) gload16(pb[c] + ko, &Bs[buf][(t + c * 256) * 8]);
  };
  fx4 acc[2][NJT] = {};
  const int nk = K >> 6;
  stage(0, 0);
  if (nk > 1) stage(1, 64);
  int cur = 0;
  for (int ki = 0; ki < nk; ++ki) {
    if (ki + 1 < nk) {
      if constexpr (BCH == 2) asm volatile("s_waitcnt vmcnt(4)" ::: "memory");
      else                    asm volatile("s_waitcnt vmcnt(6)" ::: "memory");
    } else {
      asm volatile("s_waitcnt vmcnt(0)" ::: "memory");
    }
    __builtin_amdgcn_s_barrier();
    __builtin_amdgcn_sched_barrier(0);
    asm volatile("" ::: "memory");
    if (ki + 2 < nk) {
      int b2 = cur - 1; if (b2 < 0) b2 = 2;
      stage(b2, (ki + 2) * 64);
    }
    const unsigned short* ab = &As[cur][0];
    const unsigned short* bb = &Bs[cur][0];
#pragma unroll
    for (int kk = 0; kk < 2; ++kk) {
      bf8 a0 = *(const bf8*)(ab + (((wi * 2 + 0) * 2 + kk) * 64 + lane) * 8);
      bf8 a1 = *(const bf8*)(ab + (((wi * 2 + 1) * 2 + kk) * 64 + lane) * 8);
#pragma unroll
      for (int jt = 0; jt < NJT; ++jt) {
        bf8 b = *(const bf8*)(bb + (((wj * NJT + jt) * 2 + kk) * 64 + lane) * 8);
        acc[0][jt] = __builtin_amdgcn_mfma_f32_16x16x32_bf16(a0, b, acc[0][jt], 0, 0, 0);
        acc[1][jt] = __builtin_amdgcn_mfma_f32_16x16x32_bf16(a1, b, acc[1][jt], 0, 0, 0);
      }
    }
    cur = (cur == 2) ? 0 : cur + 1;
  }
  if (FINAL) {
    // LDS transpose -> coalesced fp32 epilogue (resid + relu)
    float* sc = (float*)&Bs[0][0];  // BN x 66 floats (<= 48KB for BN=128)
    __syncthreads();
#pragma unroll
    for (int it = 0; it < 2; ++it) {
      const int lr0 = wi * 32 + it * 16 + g4 * 4;
#pragma unroll
      for (int jt = 0; jt < NJT; ++jt) {
        fx4 v = acc[it][jt];
        const int ml = wj * (BN / 2) + jt * 16 + lrow;
#pragma unroll
        for (int r = 0; r < 4; ++r) sc[ml * 66 + lr0 + r] = v[r];
      }
    }
    __syncthreads();
#pragma unroll
    for (int mi = 0; mi < BN / 4; ++mi) {
      const int m = wid * (BN / 4) + mi;
      const float val = sc[m * 66 + lane];
      const size_t gi = ((size_t)bz * M + j0 + m) * 576 + i0 + lane;
      ((float*)outp)[gi] = fmaxf(val + resid[gi], 0.f);
    }
    return;
  }
#pragma unroll
  for (int it = 0; it < 2; ++it) {
    const int row0 = i0 + wi * 32 + it * 16 + g4 * 4;
#pragma unroll
    for (int jt = 0; jt < NJT; ++jt) {
      fx4 v = acc[it][jt];
      const int m = j0 + wj * (BN / 2) + jt * 16 + lrow;
      if (BIASADD) {
        float bv = bias[m];
        v[0] += bv; v[1] += bv; v[2] += bv; v[3] += bv;
      }
      unsigned short* o = (unsigned short*)outp;
#pragma unroll
      for (int r = 0; r < 4; ++r) {
        const float ov = RELU ? fmaxf(v[r], 0.f) : v[r];
        o[((size_t)(bz * 576) + row0 + r) * M + m] = (unsigned short)f2bf1(ov);
      }
    }
  }
}
#undef ROWOF
#undef KOF

// ---------------- fused offsets -> grid-sample -> k/v proj, lane-parallel
__global__ __launch_bounds__(256, 2) void k_sample(const unsigned short* __restrict__ qT,
                                                   const unsigned short* __restrict__ h2T,
                                                   const float* __restrict__ Wdw,
                                                   const float* __restrict__ bdw,
                                                   const float* __restrict__ Wpw,
                                                   const float* __restrict__ Wk,
                                                   const float* __restrict__ Wv,
                                                   float* __restrict__ vgrid,
                                                   float* __restrict__ kT,
                                                   float* __restrict__ vT) {
  __shared__ float vg[32];                              // 16 pos x 2
  __shared__ __align__(16) unsigned short kvls[768];    // 16 pos x 48 bf16
  const int blk = blockIdx.x;
  const int bg = blk >> 2, pg = blk & 3;
  const int b = bg >> 3, g = bg & 7;
  const int t = threadIdx.x;
  const int pl = t >> 4;        // local pos 0..15
  const int cq = t & 15;        // channel slice (3 ch)
  const int pos = pg * 16 + pl;
  const int oy = pos >> 3, ox = pos & 7;
  const int ch0 = cq * 3;
  // ---- phase A: depthwise 3x3/s3 + gelu + 1x1(2) via lane-parallel reduce
  float s0 = bdw[ch0], s1 = bdw[ch0 + 1], s2 = bdw[ch0 + 2];
#pragma unroll
  for (int ky = 0; ky < 3; ++ky) {
#pragma unroll
    for (int kx = 0; kx < 3; ++kx) {
      const unsigned short* rp =
          qT + ((size_t)b * 576 + (oy * 3 + ky) * 24 + ox * 3 + kx) * 384 + g * 48 + ch0;
      const int tap = ky * 3 + kx;
      s0 = fmaf(bf2f(rp[0]), Wdw[(ch0 + 0) * 9 + tap], s0);
      s1 = fmaf(bf2f(rp[1]), Wdw[(ch0 + 1) * 9 + tap], s1);
      s2 = fmaf(bf2f(rp[2]), Wdw[(ch0 + 2) * 9 + tap], s2);
    }
  }
  float a0 = 0.f, a1 = 0.f;
  {
    const float z0 = s0, z1 = s1, z2 = s2;
    const float g0 = 0.5f * z0 * (1.f + erff(z0 * 0.70710678118654752f));
    const float g1 = 0.5f * z1 * (1.f + erff(z1 * 0.70710678118654752f));
    const float g2 = 0.5f * z2 * (1.f + erff(z2 * 0.70710678118654752f));
    a0 = g0 * Wpw[ch0] + g1 * Wpw[ch0 + 1] + g2 * Wpw[ch0 + 2];
    a1 = g0 * Wpw[48 + ch0] + g1 * Wpw[48 + ch0 + 1] + g2 * Wpw[48 + ch0 + 2];
  }
  a0 = dpp_sum16(a0);
  a1 = dpp_sum16(a1);
  const float gx = ((float)ox + tanhf(a0) * 4.f) * (2.f / 7.f) - 1.f;
  const float gy = ((float)oy + tanhf(a1) * 4.f) * (2.f / 7.f) - 1.f;
  if (cq == 0) {
    vg[pl * 2 + 0] = gx; vg[pl * 2 + 1] = gy;
    vgrid[bg * 128 + pos * 2 + 0] = gx;
    vgrid[bg * 128 + pos * 2 + 1] = gy;
  }
  __syncthreads();
  // ---- phase B: bilinear grid sample (3 ch per thread)
  {
    const float nx = vg[pl * 2 + 0], ny = vg[pl * 2 + 1];
    const float xs = ((nx + 1.f) * 24.f - 1.f) * 0.5f;
    const float ys = ((ny + 1.f) * 24.f - 1.f) * 0.5f;
    const float x0f = floorf(xs), y0f = floorf(ys);
    const float wx = xs - x0f, wy = ys - y0f;
    const int x0 = (int)x0f, y0 = (int)y0f;
    float c0a = 0.f, c1a = 0.f, c2a = 0.f;
    const float tw[4] = {(1.f - wx) * (1.f - wy), wx * (1.f - wy), (1.f - wx) * wy, wx * wy};
    const int tx[4] = {x0, x0 + 1, x0, x0 + 1};
    const int ty[4] = {y0, y0, y0 + 1, y0 + 1};
#pragma unroll
    for (int tp = 0; tp < 4; ++tp) {
      const int ix = tx[tp], iy = ty[tp];
      const float w = tw[tp] * ((ix >= 0 && ix < 24 && iy >= 0 && iy < 24) ? 1.f : 0.f);
      const int cx = min(max(ix, 0), 23), cy = min(max(iy, 0), 23);
      const unsigned short* rp = h2T + ((size_t)b * 576 + cy * 24 + cx) * 384 + g * 48 + ch0;
      c0a = fmaf(bf2f(rp[0]), w, c0a);
      c1a = fmaf(bf2f(rp[1]), w, c1a);
      c2a = fmaf(bf2f(rp[2]), w, c2a);
    }
    kvls[pl * 48 + ch0 + 0] = (unsigned short)f2bf1(c0a);
    kvls[pl * 48 + ch0 + 1] = (unsigned short)f2bf1(c1a);
    kvls[pl * 48 + ch0 + 2] = (unsigned short)f2bf1(c2a);
  }
  __syncthreads();
  // ---- phase C: k/v grouped 1x1 from LDS; 768 outputs, 3 per thread
#pragma unroll
  for (int r = 0; r < 3; ++r) {
    const int idx = t + r * 256;
    const int j = idx / 48, o = idx % 48;
    const unsigned short* rp = &kvls[j * 48];
    const float* wkp = Wk + ((size_t)g * 48 + o) * 48;
    const float* wvp = Wv + ((size_t)g * 48 + o) * 48;
    float ak = 0.f, av = 0.f;
#pragma unroll
    for (int c8 = 0; c8 < 6; ++c8) {
      ux4 u = *(const ux4*)(rp + c8 * 8);
      float va[8]; unp8(u, va);
      fx4 wk0 = *(const fx4*)(wkp + c8 * 8); fx4 wk1 = *(const fx4*)(wkp + c8 * 8 + 4);
      fx4 wv0 = *(const fx4*)(wvp + c8 * 8); fx4 wv1 = *(const fx4*)(wvp + c8 * 8 + 4);
#pragma unroll
      for (int e = 0; e < 4; ++e) {
        ak = fmaf(va[e], wk0[e], ak); ak = fmaf(va[4 + e], wk1[e], ak);
        av = fmaf(va[e], wv0[e], av); av = fmaf(va[4 + e], wv1[e], av);
      }
    }
    kT[(size_t)bg * 3072 + (pg * 16 + j) * 48 + o] = ak;
    vT[(size_t)bg * 3072 + (pg * 16 + j) * 48 + o] = av;
  }
}

// ---------------- attention (r13-proven): 8 lanes/query, 8 keys each; channel-chunked
// r15 post-mortem: 2-half variant blew past 256 VGPRs (keep[] select chains x2 halves)
// -> 152MB scratch fetch, 150us. Reverted to the single-tile no-spill structure.
__global__ __launch_bounds__(256) void k_attn(const unsigned short* __restrict__ qT,
                                              const float* __restrict__ kT,
                                              const float* __restrict__ vT,
                                              const float* __restrict__ vgrid,
                                              const float* __restrict__ Tb,
                                              unsigned short* __restrict__ aoT) {
  __shared__ __align__(16) float kls[3360];
  __shared__ __align__(16) float vls[3360];
  __shared__ float vgls[128];
  const int t = threadIdx.x;
  const int ic = blockIdx.x, h = blockIdx.y, b = blockIdx.z;
  const int bg = b * 8 + h;
  // stage K/V rows with swizzle: row j at j*52 + (j>>3)*4 floats
  {
    const int j = t >> 2, qt = t & 3;
    const float* sk = kT + (size_t)bg * 3072 + j * 48 + qt * 12;
    const float* sv = vT + (size_t)bg * 3072 + j * 48 + qt * 12;
    float* dk = kls + j * 52 + (j >> 3) * 4 + qt * 12;
    float* dv = vls + j * 52 + (j >> 3) * 4 + qt * 12;
#pragma unroll
    for (int e = 0; e < 3; ++e) {
      ((fx4*)dk)[e] = ((const fx4*)sk)[e];
      ((fx4*)dv)[e] = ((const fx4*)sv)[e];
    }
  }
  if (t < 128) vgls[t] = vgrid[bg * 128 + t];
  __syncthreads();
  const int qi = ic * 32 + (t >> 3);
  const int kg = t & 7;
  const int rowbase = kg * 420;  // kg*8*52 + kg*4
  const unsigned short* qp = qT + ((size_t)b * 576 + qi) * 384 + h * 48;
  const float scale = 0.14433756729740643f;  // 48^-0.5
  float s[8] = {0.f, 0.f, 0.f, 0.f, 0.f, 0.f, 0.f, 0.f};
#pragma unroll
  for (int c8 = 0; c8 < 6; ++c8) {
    ux4 u = *(const ux4*)(qp + c8 * 8);
    float qv[8]; unp8(u, qv);
#pragma unroll
    for (int it = 0; it < 8; ++it) {
      const float* kr = kls + rowbase + it * 52 + c8 * 8;
      fx4 k0 = *(const fx4*)kr, k1 = *(const fx4*)(kr + 4);
      s[it] = fmaf(qv[0], k0[0], s[it]); s[it] = fmaf(qv[1], k0[1], s[it]);
      s[it] = fmaf(qv[2], k0[2], s[it]); s[it] = fmaf(qv[3], k0[3], s[it]);
      s[it] = fmaf(qv[4], k1[0], s[it]); s[it] = fmaf(qv[5], k1[1], s[it]);
      s[it] = fmaf(qv[6], k1[2], s[it]); s[it] = fmaf(qv[7], k1[3], s[it]);
    }
  }
  const float qnx = (float)(qi % 24) * (2.f / 23.f) - 1.f;
  const float qny = (float)(qi / 24) * (2.f / 23.f) - 1.f;
#pragma unroll
  for (int it = 0; it < 8; ++it) {
    const int j = kg * 8 + it;
    const float pu = qnx - vgls[j * 2 + 0];
    const float pv = qny - vgls[j * 2 + 1];
    const float u = copysignf(__logf(1.f + fabsf(pu)), pu);
    const float v = copysignf(__logf(1.f + fabsf(pv)), pv);
    float tu = (u - TABLO) * TABDI;
    float tv = (v - TABLO) * TABDI;
    int iu = (int)floorf(tu); iu = min(max(iu, 0), 254);
    int iv = (int)floorf(tv); iv = min(max(iv, 0), 254);
    const float fu = tu - (float)iu;
    const float fv = tv - (float)iv;
    const float* r0 = Tb + iu * 256 + iv;
    const float a = r0[0], bb2 = r0[1], c = r0[256], d = r0[257];
    const float top = fmaf(fv, bb2 - a, a);
    const float bot = fmaf(fv, d - c, c);
    s[it] = fmaf(s[it], scale, fmaf(fu, bot - top, top));
  }
  float mx = s[0];
#pragma unroll
  for (int it = 1; it < 8; ++it) mx = fmaxf(mx, s[it]);
  mx = fmaxf(mx, __shfl_xor(mx, 1));
  mx = fmaxf(mx, __shfl_xor(mx, 2));
  mx = fmaxf(mx, __shfl_xor(mx, 4));
  float sum = 0.f;
#pragma unroll
  for (int it = 0; it < 8; ++it) { s[it] = __expf(s[it] - mx); sum += s[it]; }
  sum = sum8(sum);
  const float inv = 1.f / sum;
#pragma unroll
  for (int it = 0; it < 8; ++it) s[it] *= inv;
  float keep[8];
#pragma unroll
  for (int c8 = 0; c8 < 6; ++c8) {
    float a8[8] = {0.f, 0.f, 0.f, 0.f, 0.f, 0.f, 0.f, 0.f};
#pragma unroll
    for (int it = 0; it < 8; ++it) {
      const float p = s[it];
      const float* vr = vls + rowbase + it * 52 + c8 * 8;
      fx4 v0 = *(const fx4*)vr, v1 = *(const fx4*)(vr + 4);
      a8[0] = fmaf(p, v0[0], a8[0]); a8[1] = fmaf(p, v0[1], a8[1]);
      a8[2] = fmaf(p, v0[2], a8[2]); a8[3] = fmaf(p, v0[3], a8[3]);
      a8[4] = fmaf(p, v1[0], a8[4]); a8[5] = fmaf(p, v1[1], a8[5]);
      a8[6] = fmaf(p, v1[2], a8[6]); a8[7] = fmaf(p, v1[3], a8[7]);
    }
#pragma unroll
    for (int e = 0; e < 8; ++e) {
      a8[e] = sum8(a8[e]);
      keep[e] = (kg == c8) ? a8[e] : keep[e];
    }
  }
  if (kg < 6) {
    unsigned* op32 = (unsigned*)(aoT + ((size_t)b * 576 + qi) * 384 + h * 48 + kg * 8);
    op32[0] = cvtpk(keep[0], keep[1]);
    op32[1] = cvtpk(keep[2], keep[3]);
    op32[2] = cvtpk(keep[4], keep[5]);
    op32[3] = cvtpk(keep[6], keep[7]);
  }
}

extern "C" void kernel_launch(void* const* d_in, const int* in_sizes, int n_in,
                              void* d_out, int out_size, void* d_ws, size_t ws_size,
                              hipStream_t stream) {
  (void)in_sizes; (void)n_in; (void)out_size; (void)ws_size;
  const float* x    = (const float*)d_in[0];
  const float* W1   = (const float*)d_in[1];
  const float* W2   = (const float*)d_in[2];
  const float* W3   = (const float*)d_in[3];
  const float* W4   = (const float*)d_in[4];
  const float* Wq   = (const float*)d_in[5];
  const float* Wk   = (const float*)d_in[6];
  const float* Wv   = (const float*)d_in[7];
  const float* Wdw  = (const float*)d_in[8];
  const float* bdw  = (const float*)d_in[9];
  const float* Wpw  = (const float*)d_in[10];
  const float* cw1  = (const float*)d_in[11];
  const float* cb1  = (const float*)d_in[12];
  const float* cw2  = (const float*)d_in[13];
  const float* cb2  = (const float*)d_in[14];
  const float* cw3  = (const float*)d_in[15];
  const float* cb3  = (const float*)d_in[16];
  const float* Wout = (const float*)d_in[17];
  const float* bout = (const float*)d_in[18];

  char* ws = (char*)d_ws;
  size_t off = 0;
  auto alloc = [&](size_t bytes) {
    void* p = ws + off;
    off += (bytes + 255) & ~(size_t)255;
    return p;
  };
  unsigned short* xT  = (unsigned short*)alloc((size_t)4 * 576 * 1536 * 2);
  unsigned short* h1T = (unsigned short*)alloc((size_t)4 * 576 * 768 * 2);
  unsigned short* h2T = (unsigned short*)alloc((size_t)4 * 576 * 384 * 2);
  unsigned short* qT  = (unsigned short*)alloc((size_t)4 * 576 * 384 * 2);
  unsigned short* aoT = (unsigned short*)alloc((size_t)4 * 576 * 384 * 2);
  unsigned short* AT  = (unsigned short*)alloc((size_t)4 * 576 * 384 * 2);
  unsigned short* h3T = (unsigned short*)alloc((size_t)4 * 576 * 768 * 2);
  float* vgrid = (float*)alloc((size_t)32 * 64 * 2 * 4);
  float* kTb  = (float*)alloc((size_t)32 * 64 * 48 * 4);
  float* vTb  = (float*)alloc((size_t)32 * 64 * 48 * 4);
  float* Tb    = (float*)alloc((size_t)256 * 256 * 4);  // CPB table
  unsigned short* Wcvt = (unsigned short*)alloc((size_t)3096576 * 2);  // bf16 weights
  unsigned short* Wqd  = (unsigned short*)alloc((size_t)384 * 384 * 2);  // block-diag q weight
  const unsigned short* W1b   = Wcvt;
  const unsigned short* W2b   = Wcvt + 1179648;
  const unsigned short* W3b   = Wcvt + 1474560;
  const unsigned short* W4b   = Wcvt + 1769472;
  const unsigned short* Woutb = Wcvt + 2949120;

  k_prep<<<7456, 256, 0, stream>>>(W1, W2, W3, W4, Wout, Wq, x,
                                   cw1, cb1, cw2, cb2, cw3, cb3,
                                   (unsigned*)Wcvt, (unsigned*)Wqd, xT, Tb);
  k_gemm<128, false, false, true><<<dim3(6, 9, 4), 256, 0, stream>>>(xT, W1b, nullptr, nullptr, h1T, 1536, 768);
  k_gemm<64, false, false, true><<<dim3(6, 9, 4), 256, 0, stream>>>(h1T, W2b, nullptr, nullptr, h2T, 768, 384);
  k_gemm<64, false, false, false><<<dim3(6, 9, 4), 256, 0, stream>>>(h2T, Wqd, nullptr, nullptr, qT, 384, 384);
  k_sample<<<128, 256, 0, stream>>>(qT, h2T, Wdw, bdw, Wpw, Wk, Wv, vgrid, kTb, vTb);
  k_attn<<<dim3(18, 8, 4), 256, 0, stream>>>(qT, kTb, vTb, vgrid, Tb, aoT);
  k_gemm<64, true, false, true><<<dim3(6, 9, 4), 256, 0, stream>>>(aoT, Woutb, bout, nullptr, AT, 384, 384);
  k_gemm<128, false, false, true><<<dim3(6, 9, 4), 256, 0, stream>>>(AT, W3b, nullptr, nullptr, h3T, 384, 768);
  k_gemm<128, false, true, true><<<dim3(12, 9, 4), 256, 0, stream>>>(h3T, W4b, nullptr, x, d_out, 768, 1536);
}